// Round 8
// baseline (366.599 us; speedup 1.0000x reference)
//
#include <hip/hip_runtime.h>

#define D 128
#define TN 64
#define NC 8  // privatization copies (#XCDs)

typedef __attribute__((ext_vector_type(8))) short short8;
typedef __attribute__((ext_vector_type(4))) float f32x4;

__device__ __forceinline__ unsigned int bf16rne(float f) {
  unsigned int b = __float_as_uint(f);
  return (b + 0x7fffu + ((b >> 16) & 1u)) >> 16;
}
__device__ __forceinline__ float bf2f(unsigned int u) {
  return __uint_as_float(u << 16);
}

// ---- one-time: W[r][k][c] (+loopW at R) -> bf16, transposed [c][k], XOR-swizzled ----
__global__ __launch_bounds__(256) void rgc_prep_w(
    const float* __restrict__ W, const float* __restrict__ loopW,
    unsigned short* __restrict__ WT, int R)
{
  int tid = blockIdx.x * 256 + threadIdx.x;
  int s = tid >> 14;
  if (s > R) return;
  int rem = tid & 16383;
  int k = rem >> 7;
  int c = rem & 127;
  float v = (s < R) ? W[(size_t)s * D * D + k * D + c] : loopW[k * D + c];
  unsigned int u = bf16rne(v);
  unsigned int off = ((unsigned int)(c * D + k) * 2u) ^ (((unsigned int)(c & 7)) << 4);
  *(unsigned short*)((char*)WT + (size_t)s * D * D * 2 + off) = (unsigned short)u;
}

// ---- one-time: x -> bf16 row-major ----
__global__ __launch_bounds__(256) void rgc_prep_x(
    const float* __restrict__ x, unsigned short* __restrict__ xb, long long total8)
{
  long long i = (long long)blockIdx.x * 256 + threadIdx.x;
  if (i >= total8) return;
  float4 v0 = ((const float4*)x)[i * 2];
  float4 v1 = ((const float4*)x)[i * 2 + 1];
  uint4 u;
  u.x = bf16rne(v0.x) | (bf16rne(v0.y) << 16);
  u.y = bf16rne(v0.z) | (bf16rne(v0.w) << 16);
  u.z = bf16rne(v1.x) | (bf16rne(v1.y) << 16);
  u.w = bf16rne(v1.z) | (bf16rne(v1.w) << 16);
  ((uint4*)xb)[i] = u;
}

// ---- hist: one XCD-local atomic per edge into cnt8[(k*R+r)*N + d] ----
__global__ __launch_bounds__(256) void rgc_hist(
    const int* __restrict__ dst, int* __restrict__ cnt8, int N, int E, int R)
{
  int r = blockIdx.y;
  int e = blockIdx.x * 256 + threadIdx.x;
  if (e >= E) return;
  int k = (blockIdx.x + gridDim.x * blockIdx.y) & (NC - 1);
  int d = dst[(size_t)r * E + e];
  atomicAdd(&cnt8[((size_t)k * R + r) * N + d], 1);
}

// ---- per-chunk sums: one wave per (copy,rel,tile) chunk of 64 nodes ----
__global__ __launch_bounds__(256) void rgc_chunksum(
    const int* __restrict__ cnt8, int* __restrict__ tcnt8,
    int N, int ntiles, int nchunks)
{
  int wv = threadIdx.x >> 6, lane = threadIdx.x & 63;
  int chunk = blockIdx.x * 4 + wv;
  if (chunk >= nchunks) return;
  int row = chunk / ntiles, tile = chunk - row * ntiles;
  int node = tile * TN + lane;
  int v = (node < N) ? cnt8[(size_t)row * N + node] : 0;
#pragma unroll
  for (int o = 32; o > 0; o >>= 1) v += __shfl_xor(v, o, 64);
  if (lane == 0) tcnt8[chunk] = v;
}

// ---- exclusive scan over M chunk counts (single block, carry loop) ----
__global__ __launch_bounds__(1024) void rgc_scan(
    const int* __restrict__ cnt, int* __restrict__ ptr, int M, int total)
{
  __shared__ int buf[1024];
  __shared__ int carry_s;
  int tid = threadIdx.x;
  if (tid == 0) carry_s = 0;
  __syncthreads();
  for (int base = 0; base < M; base += 8192) {
    int c0 = carry_s;
    int v[8];
    int s = 0;
#pragma unroll
    for (int j = 0; j < 8; j++) {
      int i = base + tid * 8 + j;
      v[j] = (i < M) ? cnt[i] : 0;
      s += v[j];
    }
    buf[tid] = s;
    __syncthreads();
    for (int off = 1; off < 1024; off <<= 1) {
      int t = (tid >= off) ? buf[tid - off] : 0;
      __syncthreads();
      buf[tid] += t;
      __syncthreads();
    }
    int run = c0 + buf[tid] - s;
#pragma unroll
    for (int j = 0; j < 8; j++) {
      int i = base + tid * 8 + j;
      if (i < M) ptr[i] = run;
      run += v[j];
    }
    int tot = buf[1023];
    __syncthreads();
    if (tid == 0) carry_s = c0 + tot;
    __syncthreads();
  }
  if (tid == 0) ptr[M] = total;
}

// ---- per-(copy,rel,node) start offsets ----
__global__ __launch_bounds__(256) void rgc_offsets(
    const int* __restrict__ cnt8, const int* __restrict__ tptr8,
    int* __restrict__ off8, int N, int ntiles, int nchunks)
{
  int wv = threadIdx.x >> 6, lane = threadIdx.x & 63;
  int chunk = blockIdx.x * 4 + wv;
  if (chunk >= nchunks) return;
  int row = chunk / ntiles, tile = chunk - row * ntiles;
  int node = tile * TN + lane;
  int deg = (node < N) ? cnt8[(size_t)row * N + node] : 0;
  int v = deg;
#pragma unroll
  for (int o = 1; o < 64; o <<= 1) {
    int t = __shfl_up(v, o, 64);
    if (lane >= o) v += t;
  }
  if (node < N) off8[(size_t)row * N + node] = tptr8[chunk] + (v - deg);
}

// ---- fill: scatter src ids into copy-major node-contiguous lists ----
// off8 becomes END offsets after this kernel.
__global__ __launch_bounds__(256) void rgc_fill(
    const int* __restrict__ src, const int* __restrict__ dst,
    int* __restrict__ off8, int* __restrict__ esrc, int N, int E, int R)
{
  int r = blockIdx.y;
  int e = blockIdx.x * 256 + threadIdx.x;
  if (e >= E) return;
  int k = (blockIdx.x + gridDim.x * blockIdx.y) & (NC - 1);
  int d = dst[(size_t)r * E + e];
  int pos = atomicAdd(&off8[((size_t)k * R + r) * N + d], 1);
  esrc[pos] = src[(size_t)r * E + e];
}

// ---- fused: per tile, for each relation {register gather -> Ab} -> MFMA; self-loop; relu ----
__global__ __launch_bounds__(256) void rgc_fused(
    const unsigned short* __restrict__ xb, const unsigned short* __restrict__ WT,
    const int* __restrict__ cnt8, const int* __restrict__ off8,
    const int* __restrict__ esrc, float* __restrict__ out,
    int N, int R, int ntiles)
{
  __shared__ char Ab[TN * D * 2];  // 16 KB swizzled bf16 A tile
  __shared__ char Wb[D * D * 2];   // 32 KB swizzled bf16 W tile

  int tx = threadIdx.x;
  int tile = blockIdx.x;
  int node0 = tile * TN;
  int lane = tx & 63;
  int w = tx >> 6;
  int grp = tx >> 4, c = tx & 15;
  int sbase = lane & ~15;  // 16-lane group base within wave

  f32x4 acc[8];
#pragma unroll
  for (int i = 0; i < 8; i++) acc[i] = (f32x4){0.f, 0.f, 0.f, 0.f};

  for (int s = 0; s <= R; s++) {
    bool is_loop = (s == R);
    // stage weights (pre-swizzled, linear copy)
    const float4* wsrc = (const float4*)(WT + (size_t)s * D * D);
#pragma unroll
    for (int i = 0; i < 8; i++)
      ((float4*)Wb)[tx + i * 256] = wsrc[tx + i * 256];

    if (!is_loop) {
      // register gather for rows grp*4 .. grp*4+3; lane c owns cols 8c..8c+7
#pragma unroll
      for (int t = 0; t < 4; t++) {
        int row = grp * 4 + t;
        int node = node0 + row;
        // segment meta via one load per lane + shfl broadcast:
        // lanes 0-7: cnt of copy c; lanes 8-15: end of copy c-8
        int v = 0;
        if (node < N) {
          if (c < 8) v = cnt8[((size_t)c * R + s) * N + node];
          else       v = off8[((size_t)(c - 8) * R + s) * N + node];
        }
        float a[8];
#pragma unroll
        for (int q = 0; q < 8; q++) a[q] = 0.f;
        int deg = 0;
#pragma unroll
        for (int k = 0; k < NC; k++) {
          int cnt = __shfl(v, sbase + k, 64);
          int end = __shfl(v, sbase + 8 + k, 64);
          deg += cnt;
          for (int j = end - cnt; j < end; j++) {
            int sidx = esrc[j];
            uint4 u = ((const uint4*)(xb + (size_t)sidx * D))[c];
            a[0] += bf2f(u.x & 0xffffu); a[1] += bf2f(u.x >> 16);
            a[2] += bf2f(u.y & 0xffffu); a[3] += bf2f(u.y >> 16);
            a[4] += bf2f(u.z & 0xffffu); a[5] += bf2f(u.z >> 16);
            a[6] += bf2f(u.w & 0xffffu); a[7] += bf2f(u.w >> 16);
          }
        }
        float sc = 1.0f / fmaxf((float)deg, 1.0f);
        uint4 o;
        o.x = bf16rne(a[0] * sc) | (bf16rne(a[1] * sc) << 16);
        o.y = bf16rne(a[2] * sc) | (bf16rne(a[3] * sc) << 16);
        o.z = bf16rne(a[4] * sc) | (bf16rne(a[5] * sc) << 16);
        o.w = bf16rne(a[6] * sc) | (bf16rne(a[7] * sc) << 16);
        unsigned int off =
            ((unsigned int)(row * 256 + c * 16)) ^ (((unsigned int)(row & 7)) << 4);
        *(uint4*)(Ab + off) = o;
      }
    } else {
      // self-loop: xb rows -> Ab swizzled
#pragma unroll
      for (int it = 0; it < 4; it++) {
        int i = tx + it * 256;
        int row = i >> 4, c16 = i & 15;
        int node = node0 + row;
        uint4 u = make_uint4(0, 0, 0, 0);
        if (node < N) u = ((const uint4*)(xb + (size_t)node * D))[c16];
        unsigned int off =
            ((unsigned int)(row * 256 + c16 * 16)) ^ (((unsigned int)(row & 7)) << 4);
        *(uint4*)(Ab + off) = u;
      }
    }
    __syncthreads();  // Ab + Wb ready

    int rA = w * 16 + (lane & 15);
    unsigned int mA = (unsigned int)((rA & 7) << 4);
    unsigned int kof = (unsigned int)((lane >> 4) * 16);
    short8 afr[4];
#pragma unroll
    for (int kk = 0; kk < 4; kk++)
      afr[kk] = *(const short8*)(Ab + rA * 256 + (((unsigned int)(kk * 64) + kof) ^ mA));
#pragma unroll
    for (int ct = 0; ct < 8; ct++) {
      int rB = ct * 16 + (lane & 15);
      unsigned int mB = (unsigned int)((rB & 7) << 4);
#pragma unroll
      for (int kk = 0; kk < 4; kk++) {
        short8 b = *(const short8*)(Wb + rB * 256 + (((unsigned int)(kk * 64) + kof) ^ mB));
        acc[ct] = __builtin_amdgcn_mfma_f32_16x16x32_bf16(afr[kk], b, acc[ct], 0, 0, 0);
      }
    }
    __syncthreads();  // MFMA reads done before next phase overwrites
  }

  // epilogue: relu + store (C/D: col=lane&15, row=(lane>>4)*4+reg)
  int colb = lane & 15;
  int rowb = (lane >> 4) * 4;
#pragma unroll
  for (int ct = 0; ct < 8; ct++) {
#pragma unroll
    for (int j = 0; j < 4; j++) {
      int node = node0 + w * 16 + rowb + j;
      if (node < N)
        out[(size_t)node * D + ct * 16 + colb] = fmaxf(acc[ct][j], 0.f);
    }
  }
}

extern "C" void kernel_launch(void* const* d_in, const int* in_sizes, int n_in,
                              void* d_out, int out_size, void* d_ws, size_t ws_size,
                              hipStream_t stream)
{
  const float* x     = (const float*)d_in[0];
  const float* W     = (const float*)d_in[1];
  const float* loopW = (const float*)d_in[2];
  const int*   src   = (const int*)d_in[3];
  const int*   dst   = (const int*)d_in[4];
  float* out = (float*)d_out;

  int N = in_sizes[0] / D;        // 100000
  int R = in_sizes[1] / (D * D);  // 4
  int E = in_sizes[3] / R;        // 160000
  int ntiles = (N + TN - 1) / TN;

  // layout: cnt8 | off8 | tcnt8 | tptr8 | esrc | WT | xb   (~54 MB)
  size_t o_cnt8  = 0;
  size_t o_off8  = (o_cnt8 + (size_t)NC * R * N * 4 + 15) & ~(size_t)15;
  size_t o_tcnt8 = (o_off8 + (size_t)NC * R * N * 4 + 15) & ~(size_t)15;
  size_t o_tptr8 = (o_tcnt8 + (size_t)NC * R * ntiles * 4 + 15) & ~(size_t)15;
  size_t o_esrc  = (o_tptr8 + ((size_t)NC * R * ntiles + 1) * 4 + 15) & ~(size_t)15;
  size_t o_wt    = (o_esrc + (size_t)R * E * 4 + 15) & ~(size_t)15;
  size_t o_xb    = (o_wt + (size_t)(R + 1) * D * D * 2 + 15) & ~(size_t)15;

  char* wsb = (char*)d_ws;
  int*  cnt8  = (int*)(wsb + o_cnt8);
  int*  off8  = (int*)(wsb + o_off8);
  int*  tcnt8 = (int*)(wsb + o_tcnt8);
  int*  tptr8 = (int*)(wsb + o_tptr8);
  int*  esrc  = (int*)(wsb + o_esrc);
  unsigned short* WT = (unsigned short*)(wsb + o_wt);
  unsigned short* xb = (unsigned short*)(wsb + o_xb);

  rgc_prep_w<<<((R + 1) * D * D + 255) / 256, 256, 0, stream>>>(W, loopW, WT, R);
  long long total8 = (long long)N * D / 8;
  rgc_prep_x<<<(int)((total8 + 255) / 256), 256, 0, stream>>>(x, xb, total8);

  hipMemsetAsync(cnt8, 0, (size_t)NC * R * N * 4, stream);
  dim3 egrid((E + 255) / 256, R);
  rgc_hist<<<egrid, 256, 0, stream>>>(dst, cnt8, N, E, R);
  int nchunks = NC * R * ntiles;
  rgc_chunksum<<<(nchunks + 3) / 4, 256, 0, stream>>>(cnt8, tcnt8, N, ntiles, nchunks);
  rgc_scan<<<1, 1024, 0, stream>>>(tcnt8, tptr8, nchunks, R * E);
  rgc_offsets<<<(nchunks + 3) / 4, 256, 0, stream>>>(cnt8, tptr8, off8, N, ntiles, nchunks);
  rgc_fill<<<egrid, 256, 0, stream>>>(src, dst, off8, esrc, N, E, R);

  rgc_fused<<<ntiles, 256, 0, stream>>>(xb, WT, cnt8, off8, esrc, out, N, R, ntiles);
}

// Round 9
// 257.393 us; speedup vs baseline: 1.4243x; 1.4243x over previous
//
#include <hip/hip_runtime.h>

#define D 128
#define TN 64
#define NC 8  // privatization copies (#XCDs)

typedef __attribute__((ext_vector_type(8))) short short8;
typedef __attribute__((ext_vector_type(4))) float f32x4;

__device__ __forceinline__ unsigned int bf16rne(float f) {
  unsigned int b = __float_as_uint(f);
  return (b + 0x7fffu + ((b >> 16) & 1u)) >> 16;
}
__device__ __forceinline__ float bf2f(unsigned int u) {
  return __uint_as_float(u << 16);
}

// ---- one-time: W[r][k][c] (+loopW at R) -> bf16, transposed [c][k], XOR-swizzled ----
__global__ __launch_bounds__(256) void rgc_prep_w(
    const float* __restrict__ W, const float* __restrict__ loopW,
    unsigned short* __restrict__ WT, int R)
{
  int tid = blockIdx.x * 256 + threadIdx.x;
  int s = tid >> 14;
  if (s > R) return;
  int rem = tid & 16383;
  int k = rem >> 7;
  int c = rem & 127;
  float v = (s < R) ? W[(size_t)s * D * D + k * D + c] : loopW[k * D + c];
  unsigned int u = bf16rne(v);
  unsigned int off = ((unsigned int)(c * D + k) * 2u) ^ (((unsigned int)(c & 7)) << 4);
  *(unsigned short*)((char*)WT + (size_t)s * D * D * 2 + off) = (unsigned short)u;
}

// ---- one-time: x -> bf16 row-major ----
__global__ __launch_bounds__(256) void rgc_prep_x(
    const float* __restrict__ x, unsigned short* __restrict__ xb, long long total8)
{
  long long i = (long long)blockIdx.x * 256 + threadIdx.x;
  if (i >= total8) return;
  float4 v0 = ((const float4*)x)[i * 2];
  float4 v1 = ((const float4*)x)[i * 2 + 1];
  uint4 u;
  u.x = bf16rne(v0.x) | (bf16rne(v0.y) << 16);
  u.y = bf16rne(v0.z) | (bf16rne(v0.w) << 16);
  u.z = bf16rne(v1.x) | (bf16rne(v1.y) << 16);
  u.w = bf16rne(v1.z) | (bf16rne(v1.w) << 16);
  ((uint4*)xb)[i] = u;
}

// ---- hist: one XCD-local atomic per edge into cnt8[(k*R+r)*N + d] ----
__global__ __launch_bounds__(256) void rgc_hist(
    const int* __restrict__ dst, int* __restrict__ cnt8, int N, int E, int R)
{
  int r = blockIdx.y;
  int e = blockIdx.x * 256 + threadIdx.x;
  if (e >= E) return;
  int k = (blockIdx.x + gridDim.x * blockIdx.y) & (NC - 1);
  int d = dst[(size_t)r * E + e];
  atomicAdd(&cnt8[((size_t)k * R + r) * N + d], 1);
}

// ---- offsets: one wave per (rel,tile) chunk of 64 nodes.
// Node-major esrc layout: per-node contiguous list, per-copy sub-segments adjacent.
// Chunk base allocated by atomic bump on rowctr[r] (order irrelevant; capacity = E exact).
__global__ __launch_bounds__(256) void rgc_offsets(
    const int* __restrict__ cnt8, int* __restrict__ rowctr,
    int* __restrict__ off8, int* __restrict__ nodeptr, int* __restrict__ degv,
    int N, int E, int R, int ntiles, int nchunks)
{
  int wv = threadIdx.x >> 6, lane = threadIdx.x & 63;
  int chunk = blockIdx.x * 4 + wv;
  if (chunk >= nchunks) return;
  int r = chunk / ntiles, tile = chunk - r * ntiles;
  int node = tile * TN + lane;

  int ck[NC];
  int deg = 0;
  if (node < N) {
#pragma unroll
    for (int k = 0; k < NC; k++) {
      ck[k] = cnt8[((size_t)k * R + r) * N + node];
      deg += ck[k];
    }
  } else {
#pragma unroll
    for (int k = 0; k < NC; k++) ck[k] = 0;
  }
  // inclusive wave prefix of deg
  int v = deg;
#pragma unroll
  for (int o = 1; o < 64; o <<= 1) {
    int t = __shfl_up(v, o, 64);
    if (lane >= o) v += t;
  }
  int total = __shfl(v, 63, 64);
  int base = 0;
  if (lane == 0) base = atomicAdd(&rowctr[r], total);
  base = __shfl(base, 0, 64);
  int start = r * E + base + (v - deg);

  if (node < N) {
    nodeptr[(size_t)r * N + node] = start;
    degv[(size_t)r * N + node] = deg;
    int run = start;
#pragma unroll
    for (int k = 0; k < NC; k++) {
      off8[((size_t)k * R + r) * N + node] = run;
      run += ck[k];
    }
  }
}

// ---- fill: scatter src ids; atomics stay per-copy (XCD-local) ----
__global__ __launch_bounds__(256) void rgc_fill(
    const int* __restrict__ src, const int* __restrict__ dst,
    int* __restrict__ off8, int* __restrict__ esrc, int N, int E, int R)
{
  int r = blockIdx.y;
  int e = blockIdx.x * 256 + threadIdx.x;
  if (e >= E) return;
  int k = (blockIdx.x + gridDim.x * blockIdx.y) & (NC - 1);
  int d = dst[(size_t)r * E + e];
  int pos = atomicAdd(&off8[((size_t)k * R + r) * N + d], 1);
  esrc[pos] = src[(size_t)r * E + e];
}

// ---- aggregation: register-only gather over ONE segment/node -> swizzled bf16 Ahat ----
__global__ __launch_bounds__(256) void rgc_agg(
    const unsigned short* __restrict__ xb, const int* __restrict__ nodeptr,
    const int* __restrict__ degv, const int* __restrict__ esrc,
    unsigned short* __restrict__ Ahat, int N, int R, int ntiles)
{
  int tx = threadIdx.x;
  int tile = blockIdx.x;
  int r = blockIdx.y;
  int node0 = tile * TN;
  int grp = tx >> 4, c = tx & 15;
  char* dstp = (char*)(Ahat + ((size_t)tile * R + r) * (TN * D));

#pragma unroll
  for (int t = 0; t < 4; t++) {
    int row = grp * 4 + t;
    int node = node0 + row;
    float a[8];
#pragma unroll
    for (int q = 0; q < 8; q++) a[q] = 0.f;
    int deg = 0;
    if (node < N) {
      int st = nodeptr[(size_t)r * N + node];
      deg = degv[(size_t)r * N + node];
      for (int j = 0; j < deg; j++) {
        int s = esrc[st + j];
        uint4 u = ((const uint4*)(xb + (size_t)s * D))[c];
        a[0] += bf2f(u.x & 0xffffu); a[1] += bf2f(u.x >> 16);
        a[2] += bf2f(u.y & 0xffffu); a[3] += bf2f(u.y >> 16);
        a[4] += bf2f(u.z & 0xffffu); a[5] += bf2f(u.z >> 16);
        a[6] += bf2f(u.w & 0xffffu); a[7] += bf2f(u.w >> 16);
      }
    }
    float sc = 1.0f / fmaxf((float)deg, 1.0f);
    uint4 o;
    o.x = bf16rne(a[0] * sc) | (bf16rne(a[1] * sc) << 16);
    o.y = bf16rne(a[2] * sc) | (bf16rne(a[3] * sc) << 16);
    o.z = bf16rne(a[4] * sc) | (bf16rne(a[5] * sc) << 16);
    o.w = bf16rne(a[6] * sc) | (bf16rne(a[7] * sc) << 16);
    unsigned int off =
        ((unsigned int)(row * 256 + c * 16)) ^ (((unsigned int)(row & 7)) << 4);
    *(uint4*)(dstp + off) = o;
  }
}

// ---- GEMM: out_tile = relu(sum_r Ahat_r @ W_r + xb @ loopW) ----
__global__ __launch_bounds__(256) void rgc_gemm(
    const unsigned short* __restrict__ xb, const unsigned short* __restrict__ WT,
    const unsigned short* __restrict__ Ahat, float* __restrict__ out,
    int N, int R, int ntiles)
{
  __shared__ char Ab[TN * D * 2];  // 16 KB
  __shared__ char Wb[D * D * 2];   // 32 KB

  int tx = threadIdx.x;
  int tile = blockIdx.x;
  int node0 = tile * TN;
  int lane = tx & 63;
  int w = tx >> 6;

  f32x4 acc[8];
#pragma unroll
  for (int i = 0; i < 8; i++) acc[i] = (f32x4){0.f, 0.f, 0.f, 0.f};

  for (int s = 0; s <= R; s++) {
    bool is_loop = (s == R);
    if (!is_loop) {
      const float4* asrc = (const float4*)(Ahat + ((size_t)tile * R + s) * (TN * D));
#pragma unroll
      for (int i = 0; i < 4; i++)
        ((float4*)Ab)[tx + i * 256] = asrc[tx + i * 256];
    } else {
#pragma unroll
      for (int it = 0; it < 4; it++) {
        int i = tx + it * 256;
        int row = i >> 4, c16 = i & 15;
        int node = node0 + row;
        uint4 u = make_uint4(0, 0, 0, 0);
        if (node < N) u = ((const uint4*)(xb + (size_t)node * D))[c16];
        unsigned int off =
            ((unsigned int)(row * 256 + c16 * 16)) ^ (((unsigned int)(row & 7)) << 4);
        *(uint4*)(Ab + off) = u;
      }
    }
    const float4* wsrc = (const float4*)(WT + (size_t)s * D * D);
#pragma unroll
    for (int i = 0; i < 8; i++)
      ((float4*)Wb)[tx + i * 256] = wsrc[tx + i * 256];
    __syncthreads();

    int rA = w * 16 + (lane & 15);
    unsigned int mA = (unsigned int)((rA & 7) << 4);
    unsigned int kof = (unsigned int)((lane >> 4) * 16);
    short8 afr[4];
#pragma unroll
    for (int kk = 0; kk < 4; kk++)
      afr[kk] = *(const short8*)(Ab + rA * 256 + (((unsigned int)(kk * 64) + kof) ^ mA));
#pragma unroll
    for (int ct = 0; ct < 8; ct++) {
      int rB = ct * 16 + (lane & 15);
      unsigned int mB = (unsigned int)((rB & 7) << 4);
#pragma unroll
      for (int kk = 0; kk < 4; kk++) {
        short8 b = *(const short8*)(Wb + rB * 256 + (((unsigned int)(kk * 64) + kof) ^ mB));
        acc[ct] = __builtin_amdgcn_mfma_f32_16x16x32_bf16(afr[kk], b, acc[ct], 0, 0, 0);
      }
    }
    __syncthreads();
  }

  int colb = lane & 15;
  int rowb = (lane >> 4) * 4;
#pragma unroll
  for (int ct = 0; ct < 8; ct++) {
#pragma unroll
    for (int j = 0; j < 4; j++) {
      int node = node0 + w * 16 + rowb + j;
      if (node < N)
        out[(size_t)node * D + ct * 16 + colb] = fmaxf(acc[ct][j], 0.f);
    }
  }
}

extern "C" void kernel_launch(void* const* d_in, const int* in_sizes, int n_in,
                              void* d_out, int out_size, void* d_ws, size_t ws_size,
                              hipStream_t stream)
{
  const float* x     = (const float*)d_in[0];
  const float* W     = (const float*)d_in[1];
  const float* loopW = (const float*)d_in[2];
  const int*   src   = (const int*)d_in[3];
  const int*   dst   = (const int*)d_in[4];
  float* out = (float*)d_out;

  int N = in_sizes[0] / D;        // 100000
  int R = in_sizes[1] / (D * D);  // 4
  int E = in_sizes[3] / R;        // 160000
  int ntiles = (N + TN - 1) / TN;

  // layout: cnt8 | rowctr | off8 | nodeptr | degv | esrc | WT | xb | Ahat  (~160 MB)
  size_t o_cnt8  = 0;
  size_t o_rowc  = o_cnt8 + (size_t)NC * R * N * 4;                    // memset covers both
  size_t o_off8  = (o_rowc + (size_t)R * 4 + 15) & ~(size_t)15;
  size_t o_np    = (o_off8 + (size_t)NC * R * N * 4 + 15) & ~(size_t)15;
  size_t o_deg   = (o_np + (size_t)R * N * 4 + 15) & ~(size_t)15;
  size_t o_esrc  = (o_deg + (size_t)R * N * 4 + 15) & ~(size_t)15;
  size_t o_wt    = (o_esrc + (size_t)R * E * 4 + 15) & ~(size_t)15;
  size_t o_xb    = (o_wt + (size_t)(R + 1) * D * D * 2 + 15) & ~(size_t)15;
  size_t o_ahat  = (o_xb + (size_t)N * D * 2 + 15) & ~(size_t)15;

  char* wsb = (char*)d_ws;
  int*  cnt8    = (int*)(wsb + o_cnt8);
  int*  rowctr  = (int*)(wsb + o_rowc);
  int*  off8    = (int*)(wsb + o_off8);
  int*  nodeptr = (int*)(wsb + o_np);
  int*  degv    = (int*)(wsb + o_deg);
  int*  esrc    = (int*)(wsb + o_esrc);
  unsigned short* WT   = (unsigned short*)(wsb + o_wt);
  unsigned short* xb   = (unsigned short*)(wsb + o_xb);
  unsigned short* Ahat = (unsigned short*)(wsb + o_ahat);

  rgc_prep_w<<<((R + 1) * D * D + 255) / 256, 256, 0, stream>>>(W, loopW, WT, R);
  long long total8 = (long long)N * D / 8;
  rgc_prep_x<<<(int)((total8 + 255) / 256), 256, 0, stream>>>(x, xb, total8);

  hipMemsetAsync(cnt8, 0, (size_t)NC * R * N * 4 + (size_t)R * 4, stream);
  dim3 egrid((E + 255) / 256, R);
  rgc_hist<<<egrid, 256, 0, stream>>>(dst, cnt8, N, E, R);
  int nchunks = R * ntiles;
  rgc_offsets<<<(nchunks + 3) / 4, 256, 0, stream>>>(
      cnt8, rowctr, off8, nodeptr, degv, N, E, R, ntiles, nchunks);
  rgc_fill<<<egrid, 256, 0, stream>>>(src, dst, off8, esrc, N, E, R);

  dim3 agrid(ntiles, R);
  rgc_agg<<<agrid, 256, 0, stream>>>(xb, nodeptr, degv, esrc, Ahat, N, R, ntiles);
  rgc_gemm<<<ntiles, 256, 0, stream>>>(xb, WT, Ahat, out, N, R, ntiles);
}

// Round 10
// 212.427 us; speedup vs baseline: 1.7258x; 1.2117x over previous
//
#include <hip/hip_runtime.h>

#define D 128
#define TN 64
#define NC 8  // privatization copies (#XCDs)

typedef __attribute__((ext_vector_type(8))) short short8;
typedef __attribute__((ext_vector_type(4))) float f32x4;

__device__ __forceinline__ unsigned int bf16rne(float f) {
  unsigned int b = __float_as_uint(f);
  return (b + 0x7fffu + ((b >> 16) & 1u)) >> 16;
}
__device__ __forceinline__ float bf2f(unsigned int u) {
  return __uint_as_float(u << 16);
}

// ---- one-time: W[r][k][c] (+loopW at R) -> bf16, transposed [c][k], XOR-swizzled ----
__global__ __launch_bounds__(256) void rgc_prep_w(
    const float* __restrict__ W, const float* __restrict__ loopW,
    unsigned short* __restrict__ WT, int R)
{
  int tid = blockIdx.x * 256 + threadIdx.x;
  int s = tid >> 14;
  if (s > R) return;
  int rem = tid & 16383;
  int k = rem >> 7;
  int c = rem & 127;
  float v = (s < R) ? W[(size_t)s * D * D + k * D + c] : loopW[k * D + c];
  unsigned int u = bf16rne(v);
  unsigned int off = ((unsigned int)(c * D + k) * 2u) ^ (((unsigned int)(c & 7)) << 4);
  *(unsigned short*)((char*)WT + (size_t)s * D * D * 2 + off) = (unsigned short)u;
}

// ---- one-time: x -> bf16 row-major ----
__global__ __launch_bounds__(256) void rgc_prep_x(
    const float* __restrict__ x, unsigned short* __restrict__ xb, long long total8)
{
  long long i = (long long)blockIdx.x * 256 + threadIdx.x;
  if (i >= total8) return;
  float4 v0 = ((const float4*)x)[i * 2];
  float4 v1 = ((const float4*)x)[i * 2 + 1];
  uint4 u;
  u.x = bf16rne(v0.x) | (bf16rne(v0.y) << 16);
  u.y = bf16rne(v0.z) | (bf16rne(v0.w) << 16);
  u.z = bf16rne(v1.x) | (bf16rne(v1.y) << 16);
  u.w = bf16rne(v1.z) | (bf16rne(v1.w) << 16);
  ((uint4*)xb)[i] = u;
}

// ---- hist: one XCD-local atomic per edge into cnt8[(k*R+r)*N + d] ----
__global__ __launch_bounds__(256) void rgc_hist(
    const int* __restrict__ dst, int* __restrict__ cnt8, int N, int E, int R)
{
  int r = blockIdx.y;
  int e = blockIdx.x * 256 + threadIdx.x;
  if (e >= E) return;
  int k = (blockIdx.x + gridDim.x * blockIdx.y) & (NC - 1);
  int d = dst[(size_t)r * E + e];
  atomicAdd(&cnt8[((size_t)k * R + r) * N + d], 1);
}

// ---- offsets: one wave per (rel,tile) chunk of 64 nodes.
// Node-major esrc layout; chunk base from PER-XCD bump counter rowctr8[k][r]
// (k = block's XCD slot -> atomic stays in that XCD's L2). Region (k,r) has
// private capacity E in esrc, so disjointness needs no cross-shard coordination.
__global__ __launch_bounds__(256) void rgc_offsets(
    const int* __restrict__ cnt8, int* __restrict__ rowctr8,
    int* __restrict__ off8, int* __restrict__ nodeptr, int* __restrict__ degv,
    int N, int E, int R, int ntiles, int nchunks)
{
  int wv = threadIdx.x >> 6, lane = threadIdx.x & 63;
  int chunk = blockIdx.x * 4 + wv;
  if (chunk >= nchunks) return;
  int kx = blockIdx.x & (NC - 1);  // same for all 4 waves -> block's XCD
  int r = chunk / ntiles, tile = chunk - r * ntiles;
  int node = tile * TN + lane;

  int ck[NC];
  int deg = 0;
  if (node < N) {
#pragma unroll
    for (int k = 0; k < NC; k++) {
      ck[k] = cnt8[((size_t)k * R + r) * N + node];
      deg += ck[k];
    }
  } else {
#pragma unroll
    for (int k = 0; k < NC; k++) ck[k] = 0;
  }
  // inclusive wave prefix of deg
  int v = deg;
#pragma unroll
  for (int o = 1; o < 64; o <<= 1) {
    int t = __shfl_up(v, o, 64);
    if (lane >= o) v += t;
  }
  int total = __shfl(v, 63, 64);
  int base = 0;
  if (lane == 0) base = atomicAdd(&rowctr8[kx * R + r], total);
  base = __shfl(base, 0, 64);
  int start = (kx * R + r) * E + base + (v - deg);

  if (node < N) {
    nodeptr[(size_t)r * N + node] = start;
    degv[(size_t)r * N + node] = deg;
    int run = start;
#pragma unroll
    for (int k = 0; k < NC; k++) {
      off8[((size_t)k * R + r) * N + node] = run;
      run += ck[k];
    }
  }
}

// ---- fill: scatter src ids; atomics stay per-copy (XCD-local) ----
__global__ __launch_bounds__(256) void rgc_fill(
    const int* __restrict__ src, const int* __restrict__ dst,
    int* __restrict__ off8, int* __restrict__ esrc, int N, int E, int R)
{
  int r = blockIdx.y;
  int e = blockIdx.x * 256 + threadIdx.x;
  if (e >= E) return;
  int k = (blockIdx.x + gridDim.x * blockIdx.y) & (NC - 1);
  int d = dst[(size_t)r * E + e];
  int pos = atomicAdd(&off8[((size_t)k * R + r) * N + d], 1);
  esrc[pos] = src[(size_t)r * E + e];
}

// ---- aggregation: register-only gather over ONE segment/node -> swizzled bf16 Ahat ----
__global__ __launch_bounds__(256) void rgc_agg(
    const unsigned short* __restrict__ xb, const int* __restrict__ nodeptr,
    const int* __restrict__ degv, const int* __restrict__ esrc,
    unsigned short* __restrict__ Ahat, int N, int R, int ntiles)
{
  int tx = threadIdx.x;
  int tile = blockIdx.x;
  int r = blockIdx.y;
  int node0 = tile * TN;
  int grp = tx >> 4, c = tx & 15;
  char* dstp = (char*)(Ahat + ((size_t)tile * R + r) * (TN * D));

#pragma unroll
  for (int t = 0; t < 4; t++) {
    int row = grp * 4 + t;
    int node = node0 + row;
    float a[8];
#pragma unroll
    for (int q = 0; q < 8; q++) a[q] = 0.f;
    int deg = 0;
    if (node < N) {
      int st = nodeptr[(size_t)r * N + node];
      deg = degv[(size_t)r * N + node];
      for (int j = 0; j < deg; j++) {
        int s = esrc[st + j];
        uint4 u = ((const uint4*)(xb + (size_t)s * D))[c];
        a[0] += bf2f(u.x & 0xffffu); a[1] += bf2f(u.x >> 16);
        a[2] += bf2f(u.y & 0xffffu); a[3] += bf2f(u.y >> 16);
        a[4] += bf2f(u.z & 0xffffu); a[5] += bf2f(u.z >> 16);
        a[6] += bf2f(u.w & 0xffffu); a[7] += bf2f(u.w >> 16);
      }
    }
    float sc = 1.0f / fmaxf((float)deg, 1.0f);
    uint4 o;
    o.x = bf16rne(a[0] * sc) | (bf16rne(a[1] * sc) << 16);
    o.y = bf16rne(a[2] * sc) | (bf16rne(a[3] * sc) << 16);
    o.z = bf16rne(a[4] * sc) | (bf16rne(a[5] * sc) << 16);
    o.w = bf16rne(a[6] * sc) | (bf16rne(a[7] * sc) << 16);
    unsigned int off =
        ((unsigned int)(row * 256 + c * 16)) ^ (((unsigned int)(row & 7)) << 4);
    *(uint4*)(dstp + off) = o;
  }
}

// ---- GEMM: out_tile = relu(sum_r Ahat_r @ W_r + xb @ loopW) ----
__global__ __launch_bounds__(256) void rgc_gemm(
    const unsigned short* __restrict__ xb, const unsigned short* __restrict__ WT,
    const unsigned short* __restrict__ Ahat, float* __restrict__ out,
    int N, int R, int ntiles)
{
  __shared__ char Ab[TN * D * 2];  // 16 KB
  __shared__ char Wb[D * D * 2];   // 32 KB

  int tx = threadIdx.x;
  int tile = blockIdx.x;
  int node0 = tile * TN;
  int lane = tx & 63;
  int w = tx >> 6;

  f32x4 acc[8];
#pragma unroll
  for (int i = 0; i < 8; i++) acc[i] = (f32x4){0.f, 0.f, 0.f, 0.f};

  for (int s = 0; s <= R; s++) {
    bool is_loop = (s == R);
    if (!is_loop) {
      const float4* asrc = (const float4*)(Ahat + ((size_t)tile * R + s) * (TN * D));
#pragma unroll
      for (int i = 0; i < 4; i++)
        ((float4*)Ab)[tx + i * 256] = asrc[tx + i * 256];
    } else {
#pragma unroll
      for (int it = 0; it < 4; it++) {
        int i = tx + it * 256;
        int row = i >> 4, c16 = i & 15;
        int node = node0 + row;
        uint4 u = make_uint4(0, 0, 0, 0);
        if (node < N) u = ((const uint4*)(xb + (size_t)node * D))[c16];
        unsigned int off =
            ((unsigned int)(row * 256 + c16 * 16)) ^ (((unsigned int)(row & 7)) << 4);
        *(uint4*)(Ab + off) = u;
      }
    }
    const float4* wsrc = (const float4*)(WT + (size_t)s * D * D);
#pragma unroll
    for (int i = 0; i < 8; i++)
      ((float4*)Wb)[tx + i * 256] = wsrc[tx + i * 256];
    __syncthreads();

    int rA = w * 16 + (lane & 15);
    unsigned int mA = (unsigned int)((rA & 7) << 4);
    unsigned int kof = (unsigned int)((lane >> 4) * 16);
    short8 afr[4];
#pragma unroll
    for (int kk = 0; kk < 4; kk++)
      afr[kk] = *(const short8*)(Ab + rA * 256 + (((unsigned int)(kk * 64) + kof) ^ mA));
#pragma unroll
    for (int ct = 0; ct < 8; ct++) {
      int rB = ct * 16 + (lane & 15);
      unsigned int mB = (unsigned int)((rB & 7) << 4);
#pragma unroll
      for (int kk = 0; kk < 4; kk++) {
        short8 b = *(const short8*)(Wb + rB * 256 + (((unsigned int)(kk * 64) + kof) ^ mB));
        acc[ct] = __builtin_amdgcn_mfma_f32_16x16x32_bf16(afr[kk], b, acc[ct], 0, 0, 0);
      }
    }
    __syncthreads();
  }

  int colb = lane & 15;
  int rowb = (lane >> 4) * 4;
#pragma unroll
  for (int ct = 0; ct < 8; ct++) {
#pragma unroll
    for (int j = 0; j < 4; j++) {
      int node = node0 + w * 16 + rowb + j;
      if (node < N)
        out[(size_t)node * D + ct * 16 + colb] = fmaxf(acc[ct][j], 0.f);
    }
  }
}

extern "C" void kernel_launch(void* const* d_in, const int* in_sizes, int n_in,
                              void* d_out, int out_size, void* d_ws, size_t ws_size,
                              hipStream_t stream)
{
  const float* x     = (const float*)d_in[0];
  const float* W     = (const float*)d_in[1];
  const float* loopW = (const float*)d_in[2];
  const int*   src   = (const int*)d_in[3];
  const int*   dst   = (const int*)d_in[4];
  float* out = (float*)d_out;

  int N = in_sizes[0] / D;        // 100000
  int R = in_sizes[1] / (D * D);  // 4
  int E = in_sizes[3] / R;        // 160000
  int ntiles = (N + TN - 1) / TN;

  // layout: cnt8 | rowctr8 | off8 | nodeptr | degv | esrc[NC*R*E] | WT | xb | Ahat (~180 MB)
  size_t o_cnt8  = 0;
  size_t o_rowc  = o_cnt8 + (size_t)NC * R * N * 4;                 // memset covers both
  size_t o_off8  = (o_rowc + (size_t)NC * R * 4 + 15) & ~(size_t)15;
  size_t o_np    = (o_off8 + (size_t)NC * R * N * 4 + 15) & ~(size_t)15;
  size_t o_deg   = (o_np + (size_t)R * N * 4 + 15) & ~(size_t)15;
  size_t o_esrc  = (o_deg + (size_t)R * N * 4 + 15) & ~(size_t)15;
  size_t o_wt    = (o_esrc + (size_t)NC * R * E * 4 + 15) & ~(size_t)15;
  size_t o_xb    = (o_wt + (size_t)(R + 1) * D * D * 2 + 15) & ~(size_t)15;
  size_t o_ahat  = (o_xb + (size_t)N * D * 2 + 15) & ~(size_t)15;

  char* wsb = (char*)d_ws;
  int*  cnt8    = (int*)(wsb + o_cnt8);
  int*  rowctr8 = (int*)(wsb + o_rowc);
  int*  off8    = (int*)(wsb + o_off8);
  int*  nodeptr = (int*)(wsb + o_np);
  int*  degv    = (int*)(wsb + o_deg);
  int*  esrc    = (int*)(wsb + o_esrc);
  unsigned short* WT   = (unsigned short*)(wsb + o_wt);
  unsigned short* xb   = (unsigned short*)(wsb + o_xb);
  unsigned short* Ahat = (unsigned short*)(wsb + o_ahat);

  rgc_prep_w<<<((R + 1) * D * D + 255) / 256, 256, 0, stream>>>(W, loopW, WT, R);
  long long total8 = (long long)N * D / 8;
  rgc_prep_x<<<(int)((total8 + 255) / 256), 256, 0, stream>>>(x, xb, total8);

  hipMemsetAsync(cnt8, 0, (size_t)NC * R * N * 4 + (size_t)NC * R * 4, stream);
  dim3 egrid((E + 255) / 256, R);
  rgc_hist<<<egrid, 256, 0, stream>>>(dst, cnt8, N, E, R);
  int nchunks = R * ntiles;
  rgc_offsets<<<(nchunks + 3) / 4, 256, 0, stream>>>(
      cnt8, rowctr8, off8, nodeptr, degv, N, E, R, ntiles, nchunks);
  rgc_fill<<<egrid, 256, 0, stream>>>(src, dst, off8, esrc, N, E, R);

  dim3 agrid(ntiles, R);
  rgc_agg<<<agrid, 256, 0, stream>>>(xb, nodeptr, degv, esrc, Ahat, N, R, ntiles);
  rgc_gemm<<<ntiles, 256, 0, stream>>>(xb, WT, Ahat, out, N, R, ntiles);
}